// Round 13
// baseline (456.781 us; speedup 1.0000x reference)
//
#include <hip/hip_runtime.h>
#include <hip/hip_bf16.h>
#include <math.h>

// AFNO2D: rfft2(128x128, ortho) -> blockdiag complex MLP (8 x 96) -> softshrink -> irfft2 -> +bias
// B=4, H=W=128, C=768.  ALL transforms are MFMA GEMMs against baked bf16 matrices.
// Planes in ws (packed bf16 re|im per uint, [b][pos=h*65+kw][c]):
//   A  = forward W-spectrum (k_fft_w; read-only afterwards)
//   Bp = working spectrum: k_ffth<1> A->Bp, k_mlp3 in-place, k_ffth<0> in-place
// Bias via spectral identity: irfft_w(rfft_w(x)) = x, so k_ifft_w transforms (A + Bp).
// v7: k_mid UNFUSED into three lean kernels. r10/r12 falsified the LDS-pool theory: the
// 2-WG blocker was total VGPR (incl. MFMA acc) > 64; instead of one barrier-heavy 1-WG/CU
// kernel, three small-LDS kernels each get 4+ WG/CU of natural overlap.

#define HD   768
#define NBLK 8
#define HH   128
#define WW   128
#define WC   65
#define NPOS (HH * WC)

constexpr float SC    = 0.08838834764831845f;      // 1/sqrt(128)
constexpr float TWOPI = 6.28318530717958647692f;

// table layout (ushort offsets from wf base)
constexpr int TM_OFF     = 0;        // H-DFT: 96 frags = part(3:cos,sin,-sin) x kot(8) x kk(4)
constexpr int TW_OFF     = 49152;    // W-rfft: 40 frags = mt(10) x kk(4)
constexpr int TWI_OFF    = 69632;    // W-irfft: 40 frags = mt(8) x kk(5)
constexpr int WF_OFF     = 90112;    // MLP: 16 (layer,n) x 72 frags (kernels use kk' 0..2 = 36)
constexpr int WF_END_U16 = 679936;   // WF_OFF + 16*72*512
constexpr size_t A_UINTS = (size_t)4 * NPOS * HD;  // 102.2 MB per plane

typedef __attribute__((ext_vector_type(8))) short short8;
typedef __attribute__((ext_vector_type(4))) float f32x4;

#define MFMA __builtin_amdgcn_mfma_f32_16x16x32_bf16

static __device__ inline unsigned short f2bf(float f) {
  __hip_bfloat16 h = __float2bfloat16(f);
  return __builtin_bit_cast(unsigned short, h);
}
static __device__ inline unsigned int pack2(float re, float im) {
  return (unsigned int)f2bf(re) | ((unsigned int)f2bf(im) << 16);
}
static __device__ inline float lo2f(unsigned int u) {
  return __builtin_bit_cast(float, u << 16);
}
static __device__ inline float hi2f(unsigned int u) {
  return __builtin_bit_cast(float, u & 0xffff0000u);
}

// ================= k_prep: bake all MFMA fragment images =================
__global__ __launch_bounds__(256) void k_prep(const float* __restrict__ w1,
                                              const float* __restrict__ b1,
                                              const float* __restrict__ w2,
                                              const float* __restrict__ b2,
                                              unsigned short* __restrict__ wf,
                                              float* __restrict__ bpk) {
  const int blk = blockIdx.x, t = threadIdx.x;
  if (blk < 16) {                      // MLP Waug B-frags (full 72) + biases
    const int layer = blk >> 3, n = blk & 7;
    const float* w  = layer ? w2 : w1;
    const float* bs = layer ? b2 : b1;
    unsigned short* dst = wf + WF_OFF + (size_t)blk * (72 * 512);
    for (int e = t; e < 72 * 512; e += 256) {
      int f = e >> 9, idx = e & 511;
      int kk = f / 12, nt = f - kk * 12;
      int lane = idx >> 3, j = idx & 7;
      int k  = kk * 32 + (lane >> 4) * 8 + j;     // 0..191
      int cc = nt * 16 + (lane & 15);             // 0..191
      float v;
      if (k < 96) v = (cc < 96) ? w[(size_t)n * 9216 + k * 96 + cc]
                                : w[(size_t)(8 + n) * 9216 + k * 96 + (cc - 96)];
      else        v = (cc < 96) ? -w[(size_t)(8 + n) * 9216 + (k - 96) * 96 + cc]
                                :  w[(size_t)n * 9216 + (k - 96) * 96 + (cc - 96)];
      dst[e] = f2bf(v);
    }
    for (int c = t; c < 192; c += 256)
      bpk[blk * 192 + c] = (c < 96) ? bs[n * 96 + c] : bs[(8 + n) * 96 + (c - 96)];
  } else if (blk == 16) {              // H-DFT twiddles: 3 parts x 32 (kot*4+kk)
    for (int e = t; e < 96 * 512; e += 256) {
      int f = e >> 9, idx = e & 511;
      int part = f >> 5, rem = f & 31, kot = rem >> 2, kk = rem & 3;
      int lane = idx >> 3, j = idx & 7;
      int ko = kot * 16 + (lane & 15);
      int r  = kk * 32 + (lane >> 4) * 8 + j;     // 0..127
      float sn, cs; sincosf((TWOPI / 128.f) * (float)((ko * r) & 127), &sn, &cs);
      float v = (part == 0) ? cs : (part == 1) ? sn : -sn;
      wf[TM_OFF + (size_t)f * 512 + idx] = f2bf(v * SC);
    }
  } else if (blk == 17) {              // W-rfft matrix: rows 0..79 = re, 80..159 = im
    for (int e = t; e < 40 * 512; e += 256) {
      int f = e >> 9, idx = e & 511;
      int mt = f >> 2, kk = f & 3;
      int lane = idx >> 3, j = idx & 7;
      int row = mt * 16 + (lane & 15);
      int r   = kk * 32 + (lane >> 4) * 8 + j;    // 0..127
      int kor = (row < 80) ? row : row - 80;
      float sn, cs; sincosf((TWOPI / 128.f) * (float)((kor * r) & 127), &sn, &cs);
      wf[TW_OFF + (size_t)f * 512 + idx] = f2bf((row < 80 ? cs : -sn) * SC);
    }
  } else {                             // W-irfft matrix: K = [re 0..79 | im 0..79]
    for (int e = t; e < 40 * 512; e += 256) {
      int f = e >> 9, idx = e & 511;
      int mt = f / 5, kk = f - mt * 5;
      int lane = idx >> 3, j = idx & 7;
      int wr = mt * 16 + (lane & 15);
      int k  = kk * 32 + (lane >> 4) * 8 + j;     // 0..159
      float v = 0.f;
      if (k < 80) {
        int kb = k;
        if (kb <= 64) {
          float sn, cs; sincosf((TWOPI / 128.f) * (float)((wr * kb) & 127), &sn, &cs);
          v = SC * ((kb == 0 || kb == 64) ? 1.f : 2.f) * cs;
        }
      } else {
        int kb = k - 80;                           // imag of bins 0,64 ignored (c2r)
        if (kb >= 1 && kb <= 63) {
          float sn, cs; sincosf((TWOPI / 128.f) * (float)((wr * kb) & 127), &sn, &cs);
          v = -2.f * SC * sn;
        }
      }
      wf[TWI_OFF + (size_t)f * 512 + idx] = f2bf(v);
    }
  }
}

// ================= k_fft_w: rfft along W via GEMM, x -> packed A =================
__global__ __launch_bounds__(256) void k_fft_w(const float* __restrict__ x,
                                               unsigned int* __restrict__ A,
                                               const unsigned short* __restrict__ wf) {
  __shared__ unsigned short Xt[64 * 136];          // [ch][r] bf16
  const int h = blockIdx.x, c0 = blockIdx.y * 64, b = blockIdx.z, t = threadIdx.x;
  const int wv = t >> 6, lane = t & 63, l15 = lane & 15, lg = lane >> 4;
  const float* xp = x + ((size_t)(b * HH + h)) * WW * HD + c0;
  for (int idx = t; idx < 128 * 64; idx += 256) {
    int r = idx >> 6, ch = idx & 63;
    Xt[ch * 136 + r] = f2bf(xp[(size_t)r * HD + ch]);
  }
  __syncthreads();
  const unsigned short* tw = wf + TW_OFF;
  f32x4 acc[10];
#pragma unroll
  for (int m = 0; m < 10; ++m) acc[m] = { 0.f, 0.f, 0.f, 0.f };
#pragma unroll
  for (int kk = 0; kk < 4; ++kk) {
    short8 bq = *(const short8*)&Xt[(wv * 16 + l15) * 136 + kk * 32 + lg * 8];
#pragma unroll
    for (int m = 0; m < 10; ++m) {
      short8 a = *(const short8*)&tw[(size_t)(m * 4 + kk) * 512 + lane * 8];
      acc[m] = MFMA(a, bq, acc[m], 0, 0, 0);
    }
  }
  unsigned int* Ao = A + ((size_t)b * NPOS + h * WC) * HD + c0 + wv * 16 + l15;
#pragma unroll
  for (int q = 0; q < 5; ++q)
#pragma unroll
    for (int r = 0; r < 4; ++r) {
      int ko = q * 16 + lg * 4 + r;
      if (ko <= 64) Ao[(size_t)ko * HD] = pack2(acc[q][r], acc[5 + q][r]);
    }
}

// ================= k_ifft_w: irfft along W of (A + Bp) via GEMM (spectral bias) ========
__global__ __launch_bounds__(256) void k_ifft_w(const unsigned int* __restrict__ A,
                                                const unsigned int* __restrict__ Bp,
                                                float* __restrict__ out,
                                                const unsigned short* __restrict__ wf) {
  __shared__ unsigned short Zt[64 * 168];          // [ch][k-stack 160]
  const int h = blockIdx.x, c0 = blockIdx.y * 64, b = blockIdx.z, t = threadIdx.x;
  const int wv = t >> 6, lane = t & 63, l15 = lane & 15, lg = lane >> 4;
  const size_t base = ((size_t)b * NPOS + h * WC) * HD + c0;
  for (int idx = t; idx < 65 * 64; idx += 256) {
    int kb = idx >> 6, ch = idx & 63;
    unsigned int uA = A[base + (size_t)kb * HD + ch];
    unsigned int uB = Bp[base + (size_t)kb * HD + ch];
    float re = lo2f(uA) + lo2f(uB);
    float im = hi2f(uA) + hi2f(uB);
    Zt[ch * 168 + kb]      = f2bf(re);
    Zt[ch * 168 + 80 + kb] = (kb == 0 || kb == 64) ? (unsigned short)0 : f2bf(im);
  }
  for (int idx = t; idx < 64 * 32; idx += 256) {   // zero-pad k 65..79 both halves
    int ch = idx >> 5, q = idx & 31;
    if (q < 30) {
      int kb = 65 + (q % 15), half = q / 15;
      Zt[ch * 168 + half * 80 + kb] = 0;
    }
  }
  __syncthreads();
  const unsigned short* twi = wf + TWI_OFF;
  f32x4 acc[8];
#pragma unroll
  for (int m = 0; m < 8; ++m) acc[m] = { 0.f, 0.f, 0.f, 0.f };
#pragma unroll
  for (int kk = 0; kk < 5; ++kk) {
    short8 bq = *(const short8*)&Zt[(wv * 16 + l15) * 168 + kk * 32 + lg * 8];
#pragma unroll
    for (int m = 0; m < 8; ++m) {
      short8 a = *(const short8*)&twi[(size_t)(m * 5 + kk) * 512 + lane * 8];
      acc[m] = MFMA(a, bq, acc[m], 0, 0, 0);
    }
  }
#pragma unroll
  for (int m = 0; m < 8; ++m)
#pragma unroll
    for (int r = 0; r < 4; ++r) {
      int wr = m * 16 + lg * 4 + r;
      size_t go = (((size_t)(b * HH + h)) * WW + wr) * HD + c0 + wv * 16 + l15;
      out[go] = acc[m][r];
    }
}

// ================= k_ffth<FWD>: H-DFT along H as lean GEMM, per (kv, 32ch) tile =========
// FWD=1: SRC=A -> DST=Bp. FWD=0 (inverse): in-place on Bp (disjoint slices per WG).
template <int FWD>
__global__ __launch_bounds__(256) void k_ffth(const unsigned int* __restrict__ SRC,
                                              unsigned int* __restrict__ DST,
                                              const unsigned short* __restrict__ wf) {
  __shared__ unsigned short Rb[32 * 136], Ib[32 * 136];   // 17.4 KB total
  const int kv = blockIdx.x, c0 = blockIdx.y * 32, b = blockIdx.z, t = threadIdx.x;
  const int w = t >> 6, lane = t & 63, l15 = lane & 15, lg = lane >> 4;
  const size_t base = (size_t)b * NPOS * HD;
  for (int idx = t; idx < 128 * 32; idx += 256) {
    int r = idx >> 5, ch = idx & 31;
    unsigned int u = SRC[base + ((size_t)r * WC + kv) * HD + c0 + ch];
    Rb[ch * 136 + r] = (unsigned short)(u & 0xffffu);
    Ib[ch * 136 + r] = (unsigned short)(u >> 16);
  }
  __syncthreads();
  const unsigned short* tm = wf + TM_OFF;
  f32x4 accR[2][2], accI[2][2];
#pragma unroll
  for (int a = 0; a < 2; ++a)
#pragma unroll
    for (int c = 0; c < 2; ++c) { accR[a][c] = {0.f,0.f,0.f,0.f}; accI[a][c] = {0.f,0.f,0.f,0.f}; }
#pragma unroll
  for (int kkr = 0; kkr < 4; ++kkr) {
    const int r0 = kkr * 32 + lg * 8;
#pragma unroll
    for (int kot2 = 0; kot2 < 2; ++kot2) {
      const int kot = w * 2 + kot2;
      short8 Ac = *(const short8*)&tm[(size_t)(0 * 32 + kot * 4 + kkr) * 512 + lane * 8];
      short8 As = *(const short8*)&tm[(size_t)(1 * 32 + kot * 4 + kkr) * 512 + lane * 8];
      short8 An = *(const short8*)&tm[(size_t)(2 * 32 + kot * 4 + kkr) * 512 + lane * 8];
#pragma unroll
      for (int cht = 0; cht < 2; ++cht) {
        short8 zr = *(const short8*)&Rb[(cht * 16 + l15) * 136 + r0];
        short8 zi = *(const short8*)&Ib[(cht * 16 + l15) * 136 + r0];
        accR[kot2][cht] = MFMA(Ac, zr, accR[kot2][cht], 0, 0, 0);
        if constexpr (FWD) {
          accR[kot2][cht] = MFMA(As, zi, accR[kot2][cht], 0, 0, 0);
          accI[kot2][cht] = MFMA(Ac, zi, accI[kot2][cht], 0, 0, 0);
          accI[kot2][cht] = MFMA(An, zr, accI[kot2][cht], 0, 0, 0);
        } else {
          accR[kot2][cht] = MFMA(An, zi, accR[kot2][cht], 0, 0, 0);
          accI[kot2][cht] = MFMA(Ac, zi, accI[kot2][cht], 0, 0, 0);
          accI[kot2][cht] = MFMA(As, zr, accI[kot2][cht], 0, 0, 0);
        }
      }
    }
  }
#pragma unroll
  for (int kot2 = 0; kot2 < 2; ++kot2)
#pragma unroll
    for (int cht = 0; cht < 2; ++cht)
#pragma unroll
      for (int r = 0; r < 4; ++r) {
        int ko = (w * 2 + kot2) * 16 + lg * 4 + r;
        DST[base + ((size_t)ko * WC + kv) * HD + c0 + cht * 16 + l15] =
            pack2(accR[kot2][cht][r], accI[kot2][cht][r]);
      }
}

// ================= k_mlp3: blockdiag MLP + softshrink, in-place on Bp ==================
// Per WG: 64 flat positions x one channel-block n. 8 waves = 4 row-tiles x 2 nt-halves.
__global__ __launch_bounds__(512) void k_mlp3(unsigned int* __restrict__ P,
                                              const unsigned short* __restrict__ wf,
                                              const float* __restrict__ bpk) {
  __shared__ unsigned short Rq[64 * 104], Iq[64 * 104];   // 26.6 KB
  __shared__ unsigned short WfL[12 * 512];                // 12.3 KB single frag buffer
  const int p0 = blockIdx.x * 64, n = blockIdx.y, b = blockIdx.z, t = threadIdx.x;
  const int w = t >> 6, lane = t & 63, l15 = lane & 15, lg = lane >> 4;
  const int rt = w >> 1, cb = (w & 1) * 3;                // row-tile 0..3, nt-half base
  const size_t gbase = ((size_t)b * NPOS + p0) * HD + n * 96;
  const unsigned short* wf1 = wf + WF_OFF + (size_t)n * (72 * 512);
  const unsigned short* wf2 = wf + WF_OFF + (size_t)(8 + n) * (72 * 512);

#define LOAD_FRAGS(SRC, KP)                                                       \
  for (int idx = t; idx < 768; idx += 512)                                        \
    ((int4*)WfL)[idx] = ((const int4*)((SRC) + (KP) * 12 * 512))[idx];

  for (int idx = t; idx < 64 * 96; idx += 512) {
    int pos = idx / 96, ch = idx - pos * 96;
    unsigned int u = P[gbase + (size_t)pos * HD + ch];
    Rq[pos * 104 + ch] = (unsigned short)(u & 0xffffu);
    Iq[pos * 104 + ch] = (unsigned short)(u >> 16);
  }
  LOAD_FRAGS(wf1, 0);
  __syncthreads();                                  // B1

  const int row_a = (rt * 16 + l15) * 104;
  f32x4 acc[6];
#pragma unroll
  for (int i = 0; i < 3; ++i) {
    float bv = bpk[n * 192 + (cb + i) * 16 + l15];
    acc[i] = { bv, bv, bv, bv };
    bv = bpk[n * 192 + (cb + i + 6) * 16 + l15];
    acc[3 + i] = { bv, bv, bv, bv };
  }

  // MFMA kk=k0 (A from Rq) and kk=k0+3 (A from Iq) vs WfL's 12 stored kk'=k0 frags
#define MLP_PAIR(k0)                                                             \
  {                                                                              \
    short8 aRf = *(const short8*)&Rq[row_a + (k0) * 32 + lg * 8];                \
    short8 aIf = *(const short8*)&Iq[row_a + (k0) * 32 + lg * 8];                \
    _Pragma("unroll")                                                            \
    for (int i = 0; i < 6; ++i) {                                                \
      int nt = cb + (i < 3 ? i : i + 3);                                         \
      short8 b0 = *(const short8*)&WfL[nt * 512 + lane * 8];                     \
      acc[i] = MFMA(aRf, b0, acc[i], 0, 0, 0);                                   \
      int nt2 = (nt < 6) ? nt + 6 : nt - 6;                                      \
      int4 nb = *(const int4*)&WfL[nt2 * 512 + lane * 8];                        \
      if (nt < 6) { nb.x ^= 0x80008000; nb.y ^= 0x80008000;                      \
                    nb.z ^= 0x80008000; nb.w ^= 0x80008000; }                    \
      acc[i] = MFMA(aIf, __builtin_bit_cast(short8, nb), acc[i], 0, 0, 0);       \
    }                                                                            \
  }

  // ---- layer 1
  MLP_PAIR(0);
  __syncthreads();                                  // B2
  LOAD_FRAGS(wf1, 1);
  __syncthreads();                                  // B3
  MLP_PAIR(1);
  __syncthreads();                                  // B4
  LOAD_FRAGS(wf1, 2);
  __syncthreads();                                  // B5
  MLP_PAIR(2);
  __syncthreads();                                  // B6 (all L1 plane + frag reads done)

  // relu -> own rows x own cols, + load L2 kk'=0
#pragma unroll
  for (int i = 0; i < 3; ++i)
#pragma unroll
    for (int r = 0; r < 4; ++r) {
      int row = rt * 16 + lg * 4 + r, ch = (cb + i) * 16 + l15;
      Rq[row * 104 + ch] = f2bf(fmaxf(acc[i][r], 0.f));
      Iq[row * 104 + ch] = f2bf(fmaxf(acc[3 + i][r], 0.f));
    }
  LOAD_FRAGS(wf2, 0);
  __syncthreads();                                  // B7

  // ---- layer 2
#pragma unroll
  for (int i = 0; i < 3; ++i) {
    float bv = bpk[(8 + n) * 192 + (cb + i) * 16 + l15];
    acc[i] = { bv, bv, bv, bv };
    bv = bpk[(8 + n) * 192 + (cb + i + 6) * 16 + l15];
    acc[3 + i] = { bv, bv, bv, bv };
  }
  MLP_PAIR(0);
  __syncthreads();                                  // B8
  LOAD_FRAGS(wf2, 1);
  __syncthreads();                                  // B9
  MLP_PAIR(1);
  __syncthreads();                                  // B10
  LOAD_FRAGS(wf2, 2);
  __syncthreads();                                  // B11
  MLP_PAIR(2);

  // ---- softshrink -> straight to global (no LDS use after)
#pragma unroll
  for (int r = 0; r < 4; ++r) {
    int pl = p0 + rt * 16 + lg * 4 + r;             // flat pos in batch
    int ku = pl / WC, kvv = pl - ku * WC;
    float kus = (ku >= 64) ? (float)(ku - 128) : (float)ku;
    float k2v = kus * kus + (float)(kvv * kvv);
    float thr = fmaxf(0.01f * expf(-0.00125f * k2v), 0.0005f);
#pragma unroll
    for (int i = 0; i < 3; ++i) {
      float mr = acc[i][r], mi = acc[3 + i][r];
      float mag = sqrtf(mr * mr + mi * mi + 1e-8f);
      float sf = fmaxf(mag - thr, 0.f) / mag;
      P[gbase + (size_t)(rt * 16 + lg * 4 + r) * HD + (cb + i) * 16 + l15] =
          pack2(mr * sf, mi * sf);
    }
  }
#undef MLP_PAIR
#undef LOAD_FRAGS
}

extern "C" void kernel_launch(void* const* d_in, const int* in_sizes, int n_in,
                              void* d_out, int out_size, void* d_ws, size_t ws_size,
                              hipStream_t stream) {
  const float* x  = (const float*)d_in[0];
  const float* w1 = (const float*)d_in[1];
  const float* b1 = (const float*)d_in[2];
  const float* w2 = (const float*)d_in[3];
  const float* b2 = (const float*)d_in[4];
  float* out = (float*)d_out;
  unsigned int* A  = (unsigned int*)d_ws;           // 102.2 MB forward spectrum
  unsigned int* Bp = A + A_UINTS;                   // 102.2 MB working spectrum

  // baked tables after the two planes (~1.4 MB) — nothing else writes there
  unsigned short* wf = (unsigned short*)(Bp + A_UINTS);
  float* bpk = (float*)(wf + WF_END_U16);

  k_prep<<<19, 256, 0, stream>>>(w1, b1, w2, b2, wf, bpk);
  k_fft_w<<<dim3(HH, HD / 64, 4), 256, 0, stream>>>(x, A, wf);
  k_ffth<1><<<dim3(WC, HD / 32, 4), 256, 0, stream>>>(A, Bp, wf);
  k_mlp3<<<dim3(NPOS / 64, NBLK, 4), 512, 0, stream>>>(Bp, wf, bpk);
  k_ffth<0><<<dim3(WC, HD / 32, 4), 256, 0, stream>>>(Bp, Bp, wf);
  k_ifft_w<<<dim3(HH, HD / 64, 4), 256, 0, stream>>>(A, Bp, out, wf);
}

// Round 14
// 419.946 us; speedup vs baseline: 1.0877x; 1.0877x over previous
//
#include <hip/hip_runtime.h>
#include <hip/hip_bf16.h>
#include <math.h>

// AFNO2D: rfft2(128x128, ortho) -> blockdiag complex MLP (8 x 96) -> softshrink -> irfft2 -> +bias
// B=4, H=W=128, C=768.  ALL transforms are MFMA GEMMs against baked bf16 matrices.
// Planes in ws (packed bf16 re|im per uint, [b][pos=h*65+kw][c]):
//   A = forward spectrum (k_fft_w; read-only afterwards), Bp = post-MLP spectrum (k_mid)
// Bias via spectral identity: irfft_w(rfft_w(x)) = x, so k_ifft_w transforms (A + Bp).
// k_mid v8: since 2 WG/CU is VGPR-impossible (r10/r12 evidence), LDS to 160KB is FREE.
// Stage a FULL layer's 72 baked frags (73.7 KB) at once: no XOR sign derivation
// (-288 VALU/thread), 7 barriers (was 12). Everything else identical to r11 (best, 405us).

#define HD   768
#define NBLK 8
#define HH   128
#define WW   128
#define WC   65
#define NPOS (HH * WC)

constexpr float SC    = 0.08838834764831845f;      // 1/sqrt(128)
constexpr float TWOPI = 6.28318530717958647692f;

// table layout (ushort offsets from wf base)
constexpr int TM_OFF     = 0;        // H-DFT: 96 frags = part(3:cos,sin,-sin) x kot(8) x kk(4)
constexpr int TW_OFF     = 49152;    // W-rfft: 40 frags = mt(10) x kk(4)
constexpr int TWI_OFF    = 69632;    // W-irfft: 40 frags = mt(8) x kk(5)
constexpr int WF_OFF     = 90112;    // MLP: 16 (layer,n) x 72 frags (full bake)
constexpr int WF_END_U16 = 679936;   // WF_OFF + 16*72*512
constexpr size_t A_UINTS = (size_t)4 * NPOS * HD;  // 102.2 MB per plane

typedef __attribute__((ext_vector_type(8))) short short8;
typedef __attribute__((ext_vector_type(4))) float f32x4;

#define MFMA __builtin_amdgcn_mfma_f32_16x16x32_bf16

static __device__ inline unsigned short f2bf(float f) {
  __hip_bfloat16 h = __float2bfloat16(f);
  return __builtin_bit_cast(unsigned short, h);
}
static __device__ inline unsigned int pack2(float re, float im) {
  return (unsigned int)f2bf(re) | ((unsigned int)f2bf(im) << 16);
}
static __device__ inline float lo2f(unsigned int u) {
  return __builtin_bit_cast(float, u << 16);
}
static __device__ inline float hi2f(unsigned int u) {
  return __builtin_bit_cast(float, u & 0xffff0000u);
}

// ================= k_prep: bake all MFMA fragment images =================
__global__ __launch_bounds__(256) void k_prep(const float* __restrict__ w1,
                                              const float* __restrict__ b1,
                                              const float* __restrict__ w2,
                                              const float* __restrict__ b2,
                                              unsigned short* __restrict__ wf,
                                              float* __restrict__ bpk) {
  const int blk = blockIdx.x, t = threadIdx.x;
  if (blk < 16) {                      // MLP Waug B-frags (full 72) + biases
    const int layer = blk >> 3, n = blk & 7;
    const float* w  = layer ? w2 : w1;
    const float* bs = layer ? b2 : b1;
    unsigned short* dst = wf + WF_OFF + (size_t)blk * (72 * 512);
    for (int e = t; e < 72 * 512; e += 256) {
      int f = e >> 9, idx = e & 511;
      int kk = f / 12, nt = f - kk * 12;
      int lane = idx >> 3, j = idx & 7;
      int k  = kk * 32 + (lane >> 4) * 8 + j;     // 0..191
      int cc = nt * 16 + (lane & 15);             // 0..191
      float v;
      if (k < 96) v = (cc < 96) ? w[(size_t)n * 9216 + k * 96 + cc]
                                : w[(size_t)(8 + n) * 9216 + k * 96 + (cc - 96)];
      else        v = (cc < 96) ? -w[(size_t)(8 + n) * 9216 + (k - 96) * 96 + cc]
                                :  w[(size_t)n * 9216 + (k - 96) * 96 + (cc - 96)];
      dst[e] = f2bf(v);
    }
    for (int c = t; c < 192; c += 256)
      bpk[blk * 192 + c] = (c < 96) ? bs[n * 96 + c] : bs[(8 + n) * 96 + (c - 96)];
  } else if (blk == 16) {              // H-DFT twiddles: 3 parts x 32 (kot*4+kk)
    for (int e = t; e < 96 * 512; e += 256) {
      int f = e >> 9, idx = e & 511;
      int part = f >> 5, rem = f & 31, kot = rem >> 2, kk = rem & 3;
      int lane = idx >> 3, j = idx & 7;
      int ko = kot * 16 + (lane & 15);
      int r  = kk * 32 + (lane >> 4) * 8 + j;     // 0..127
      float sn, cs; sincosf((TWOPI / 128.f) * (float)((ko * r) & 127), &sn, &cs);
      float v = (part == 0) ? cs : (part == 1) ? sn : -sn;
      wf[TM_OFF + (size_t)f * 512 + idx] = f2bf(v * SC);
    }
  } else if (blk == 17) {              // W-rfft matrix: rows 0..79 = re, 80..159 = im
    for (int e = t; e < 40 * 512; e += 256) {
      int f = e >> 9, idx = e & 511;
      int mt = f >> 2, kk = f & 3;
      int lane = idx >> 3, j = idx & 7;
      int row = mt * 16 + (lane & 15);
      int r   = kk * 32 + (lane >> 4) * 8 + j;    // 0..127
      int kor = (row < 80) ? row : row - 80;
      float sn, cs; sincosf((TWOPI / 128.f) * (float)((kor * r) & 127), &sn, &cs);
      wf[TW_OFF + (size_t)f * 512 + idx] = f2bf((row < 80 ? cs : -sn) * SC);
    }
  } else {                             // W-irfft matrix: K = [re 0..79 | im 0..79]
    for (int e = t; e < 40 * 512; e += 256) {
      int f = e >> 9, idx = e & 511;
      int mt = f / 5, kk = f - mt * 5;
      int lane = idx >> 3, j = idx & 7;
      int wr = mt * 16 + (lane & 15);
      int k  = kk * 32 + (lane >> 4) * 8 + j;     // 0..159
      float v = 0.f;
      if (k < 80) {
        int kb = k;
        if (kb <= 64) {
          float sn, cs; sincosf((TWOPI / 128.f) * (float)((wr * kb) & 127), &sn, &cs);
          v = SC * ((kb == 0 || kb == 64) ? 1.f : 2.f) * cs;
        }
      } else {
        int kb = k - 80;                           // imag of bins 0,64 ignored (c2r)
        if (kb >= 1 && kb <= 63) {
          float sn, cs; sincosf((TWOPI / 128.f) * (float)((wr * kb) & 127), &sn, &cs);
          v = -2.f * SC * sn;
        }
      }
      wf[TWI_OFF + (size_t)f * 512 + idx] = f2bf(v);
    }
  }
}

// ================= k_fft_w: rfft along W via GEMM, x -> packed A =================
__global__ __launch_bounds__(256) void k_fft_w(const float* __restrict__ x,
                                               unsigned int* __restrict__ A,
                                               const unsigned short* __restrict__ wf) {
  __shared__ unsigned short Xt[64 * 136];          // [ch][r] bf16
  const int h = blockIdx.x, c0 = blockIdx.y * 64, b = blockIdx.z, t = threadIdx.x;
  const int wv = t >> 6, lane = t & 63, l15 = lane & 15, lg = lane >> 4;
  const float* xp = x + ((size_t)(b * HH + h)) * WW * HD + c0;
  for (int idx = t; idx < 128 * 64; idx += 256) {
    int r = idx >> 6, ch = idx & 63;
    Xt[ch * 136 + r] = f2bf(xp[(size_t)r * HD + ch]);
  }
  __syncthreads();
  const unsigned short* tw = wf + TW_OFF;
  f32x4 acc[10];
#pragma unroll
  for (int m = 0; m < 10; ++m) acc[m] = { 0.f, 0.f, 0.f, 0.f };
#pragma unroll
  for (int kk = 0; kk < 4; ++kk) {
    short8 bq = *(const short8*)&Xt[(wv * 16 + l15) * 136 + kk * 32 + lg * 8];
#pragma unroll
    for (int m = 0; m < 10; ++m) {
      short8 a = *(const short8*)&tw[(size_t)(m * 4 + kk) * 512 + lane * 8];
      acc[m] = MFMA(a, bq, acc[m], 0, 0, 0);
    }
  }
  unsigned int* Ao = A + ((size_t)b * NPOS + h * WC) * HD + c0 + wv * 16 + l15;
#pragma unroll
  for (int q = 0; q < 5; ++q)
#pragma unroll
    for (int r = 0; r < 4; ++r) {
      int ko = q * 16 + lg * 4 + r;
      if (ko <= 64) Ao[(size_t)ko * HD] = pack2(acc[q][r], acc[5 + q][r]);
    }
}

// ================= k_ifft_w: irfft along W of (A + Bp) via GEMM (spectral bias) ========
__global__ __launch_bounds__(256) void k_ifft_w(const unsigned int* __restrict__ A,
                                                const unsigned int* __restrict__ Bp,
                                                float* __restrict__ out,
                                                const unsigned short* __restrict__ wf) {
  __shared__ unsigned short Zt[64 * 168];          // [ch][k-stack 160]
  const int h = blockIdx.x, c0 = blockIdx.y * 64, b = blockIdx.z, t = threadIdx.x;
  const int wv = t >> 6, lane = t & 63, l15 = lane & 15, lg = lane >> 4;
  const size_t base = ((size_t)b * NPOS + h * WC) * HD + c0;
  for (int idx = t; idx < 65 * 64; idx += 256) {
    int kb = idx >> 6, ch = idx & 63;
    unsigned int uA = A[base + (size_t)kb * HD + ch];
    unsigned int uB = Bp[base + (size_t)kb * HD + ch];
    float re = lo2f(uA) + lo2f(uB);
    float im = hi2f(uA) + hi2f(uB);
    Zt[ch * 168 + kb]      = f2bf(re);
    Zt[ch * 168 + 80 + kb] = (kb == 0 || kb == 64) ? (unsigned short)0 : f2bf(im);
  }
  for (int idx = t; idx < 64 * 32; idx += 256) {   // zero-pad k 65..79 both halves
    int ch = idx >> 5, q = idx & 31;
    if (q < 30) {
      int kb = 65 + (q % 15), half = q / 15;
      Zt[ch * 168 + half * 80 + kb] = 0;
    }
  }
  __syncthreads();
  const unsigned short* twi = wf + TWI_OFF;
  f32x4 acc[8];
#pragma unroll
  for (int m = 0; m < 8; ++m) acc[m] = { 0.f, 0.f, 0.f, 0.f };
#pragma unroll
  for (int kk = 0; kk < 5; ++kk) {
    short8 bq = *(const short8*)&Zt[(wv * 16 + l15) * 168 + kk * 32 + lg * 8];
#pragma unroll
    for (int m = 0; m < 8; ++m) {
      short8 a = *(const short8*)&twi[(size_t)(m * 5 + kk) * 512 + lane * 8];
      acc[m] = MFMA(a, bq, acc[m], 0, 0, 0);
    }
  }
#pragma unroll
  for (int m = 0; m < 8; ++m)
#pragma unroll
    for (int r = 0; r < 4; ++r) {
      int wr = m * 16 + lg * 4 + r;
      size_t go = (((size_t)(b * HH + h)) * WW + wr) * HD + c0 + wv * 16 + l15;
      out[go] = acc[m][r];
    }
}

// ================= k_mid: H-DFT fwd + MLP + softshrink + H-DFT inv =====================
template <int FWD>
static __device__ inline void dft_gemm16(const unsigned short* Rb, const unsigned short* Ib,
                                         const unsigned short* tm, int rt, int cb, int lane,
                                         f32x4* aR, f32x4* aI) {
  const int l15 = lane & 15, lg = lane >> 4;
#pragma unroll
  for (int kkr = 0; kkr < 4; ++kkr) {
    const int r0 = kkr * 32 + lg * 8;
    short8 Ac = *(const short8*)&tm[(size_t)(0 * 32 + rt * 4 + kkr) * 512 + lane * 8];
    short8 As = *(const short8*)&tm[(size_t)(1 * 32 + rt * 4 + kkr) * 512 + lane * 8];
    short8 An = *(const short8*)&tm[(size_t)(2 * 32 + rt * 4 + kkr) * 512 + lane * 8];
#pragma unroll
    for (int c = 0; c < 3; ++c) {
      short8 zr = *(const short8*)&Rb[((cb + c) * 16 + l15) * 136 + r0];
      short8 zi = *(const short8*)&Ib[((cb + c) * 16 + l15) * 136 + r0];
      aR[c] = MFMA(Ac, zr, aR[c], 0, 0, 0);
      if constexpr (FWD) {
        aR[c] = MFMA(As, zi, aR[c], 0, 0, 0);
        aI[c] = MFMA(Ac, zi, aI[c], 0, 0, 0);
        aI[c] = MFMA(An, zr, aI[c], 0, 0, 0);
      } else {
        aR[c] = MFMA(An, zi, aR[c], 0, 0, 0);
        aI[c] = MFMA(Ac, zi, aI[c], 0, 0, 0);
        aI[c] = MFMA(As, zr, aI[c], 0, 0, 0);
      }
    }
  }
}

__global__ __launch_bounds__(1024) void k_mid(const unsigned int* __restrict__ A,
                                              unsigned int* __restrict__ Bp,
                                              const unsigned short* __restrict__ wf,
                                              const float* __restrict__ bpk) {
  __shared__ unsigned short Rb[13312], Ib[13312];  // 53.2 KB plane (layout morphs)
  __shared__ unsigned short WfL[72 * 512];         // 73.7 KB: one FULL layer's frags
  const int kv = blockIdx.x, n = blockIdx.y, b = blockIdx.z, t = threadIdx.x;
  const int w = t >> 6, lane = t & 63, l15 = lane & 15, lg = lane >> 4;
  const int rt = w >> 1, cb = (w & 1) * 3;         // ko/row tile 0..7, nt-half base
  const size_t pbase = ((size_t)b * NPOS + kv) * HD + n * 96;
  const unsigned short* tm = wf + TM_OFF;
  const unsigned short* wf1 = wf + WF_OFF + (size_t)n * (72 * 512);
  const unsigned short* wf2 = wf + WF_OFF + (size_t)(8 + n) * (72 * 512);

  // ---- P0: stage plane [ch][r] + full layer-1 frags (4608 int4)
  for (int idx = t; idx < 128 * 96; idx += 1024) {
    int r = idx / 96, ch = idx - r * 96;
    unsigned int u = A[pbase + (size_t)r * (WC * HD) + ch];
    Rb[ch * 136 + r] = (unsigned short)(u & 0xffffu);
    Ib[ch * 136 + r] = (unsigned short)(u >> 16);
  }
  for (int idx = t; idx < 4608; idx += 1024)
    ((int4*)WfL)[idx] = ((const int4*)wf1)[idx];
  __syncthreads();                                  // B1

  // ---- P1: GEMM-1 fwd H-DFT
  f32x4 aR[3], aI[3];
#pragma unroll
  for (int c = 0; c < 3; ++c) { aR[c] = {0.f,0.f,0.f,0.f}; aI[c] = {0.f,0.f,0.f,0.f}; }
  dft_gemm16<1>(Rb, Ib, tm, rt, cb, lane, aR, aI);
  __syncthreads();                                  // B2 (plane [ch][r] reads done)

  // ---- P2: writeback as [pos][ch] (stride 104)
#pragma unroll
  for (int c = 0; c < 3; ++c)
#pragma unroll
    for (int r = 0; r < 4; ++r) {
      int row = rt * 16 + lg * 4 + r, ch = (cb + c) * 16 + l15;
      Rb[row * 104 + ch] = f2bf(aR[c][r]);
      Ib[row * 104 + ch] = f2bf(aI[c][r]);
    }
  __syncthreads();                                  // B3

  const int row_a = (rt * 16 + l15) * 104;
  f32x4 acc[6];
#pragma unroll
  for (int i = 0; i < 3; ++i) {
    float bv = bpk[n * 192 + (cb + i) * 16 + l15];
    acc[i] = { bv, bv, bv, bv };
    bv = bpk[n * 192 + (cb + i + 6) * 16 + l15];
    acc[3 + i] = { bv, bv, bv, bv };
  }

  // MLP layer step: 6 kk x 6 own-nt MFMAs, all frags resident, no sign derivation
#define MLP_LAYER()                                                              \
  _Pragma("unroll")                                                              \
  for (int kk = 0; kk < 6; ++kk) {                                               \
    short8 af = (kk < 3) ? *(const short8*)&Rb[row_a + kk * 32 + lg * 8]         \
                         : *(const short8*)&Ib[row_a + (kk - 3) * 32 + lg * 8];  \
    _Pragma("unroll")                                                            \
    for (int i = 0; i < 6; ++i) {                                                \
      int nt = cb + (i < 3 ? i : i + 3);                                         \
      short8 bf = *(const short8*)&WfL[(kk * 12 + nt) * 512 + lane * 8];         \
      acc[i] = MFMA(af, bf, acc[i], 0, 0, 0);                                    \
    }                                                                            \
  }

  // ---- P3: MLP layer 1 (no internal barriers)
  MLP_LAYER();
  __syncthreads();                                  // B4 (all L1 plane+frag reads done)

  // ---- P4: relu -> [pos][ch] + restage full layer-2 frags
#pragma unroll
  for (int i = 0; i < 3; ++i)
#pragma unroll
    for (int r = 0; r < 4; ++r) {
      int row = rt * 16 + lg * 4 + r, ch = (cb + i) * 16 + l15;
      Rb[row * 104 + ch] = f2bf(fmaxf(acc[i][r], 0.f));
      Ib[row * 104 + ch] = f2bf(fmaxf(acc[3 + i][r], 0.f));
    }
  for (int idx = t; idx < 4608; idx += 1024)
    ((int4*)WfL)[idx] = ((const int4*)wf2)[idx];
  __syncthreads();                                  // B5

  // ---- P5: MLP layer 2
#pragma unroll
  for (int i = 0; i < 3; ++i) {
    float bv = bpk[(8 + n) * 192 + (cb + i) * 16 + l15];
    acc[i] = { bv, bv, bv, bv };
    bv = bpk[(8 + n) * 192 + (cb + i + 6) * 16 + l15];
    acc[3 + i] = { bv, bv, bv, bv };
  }
  MLP_LAYER();
  __syncthreads();                                  // B6 (all L2 plane reads done)

  // ---- P6: softshrink -> [ch][ko] (stride 136)
#pragma unroll
  for (int r = 0; r < 4; ++r) {
    int ko = rt * 16 + lg * 4 + r;
    float kus = (ko >= 64) ? (float)(ko - 128) : (float)ko;
    float k2v = kus * kus + (float)(kv * kv);
    float thr = fmaxf(0.01f * expf(-0.00125f * k2v), 0.0005f);
#pragma unroll
    for (int i = 0; i < 3; ++i) {
      float mr = acc[i][r], mi = acc[3 + i][r];
      float mag = sqrtf(mr * mr + mi * mi + 1e-8f);
      float sf = fmaxf(mag - thr, 0.f) / mag;
      int ch = (cb + i) * 16 + l15;
      Rb[ch * 136 + ko] = f2bf(mr * sf);
      Ib[ch * 136 + ko] = f2bf(mi * sf);
    }
  }
  __syncthreads();                                  // B7

  // ---- P7: GEMM-2 inverse H-DFT -> Bp plane
#pragma unroll
  for (int c = 0; c < 3; ++c) { aR[c] = {0.f,0.f,0.f,0.f}; aI[c] = {0.f,0.f,0.f,0.f}; }
  dft_gemm16<0>(Rb, Ib, tm, rt, cb, lane, aR, aI);
#pragma unroll
  for (int c = 0; c < 3; ++c)
#pragma unroll
    for (int r = 0; r < 4; ++r) {
      int rr = rt * 16 + lg * 4 + r, ch = (cb + c) * 16 + l15;
      Bp[pbase + (size_t)rr * (WC * HD) + ch] = pack2(aR[c][r], aI[c][r]);
    }
#undef MLP_LAYER
}

extern "C" void kernel_launch(void* const* d_in, const int* in_sizes, int n_in,
                              void* d_out, int out_size, void* d_ws, size_t ws_size,
                              hipStream_t stream) {
  const float* x  = (const float*)d_in[0];
  const float* w1 = (const float*)d_in[1];
  const float* b1 = (const float*)d_in[2];
  const float* w2 = (const float*)d_in[3];
  const float* b2 = (const float*)d_in[4];
  float* out = (float*)d_out;
  unsigned int* A  = (unsigned int*)d_ws;           // 102.2 MB forward spectrum
  unsigned int* Bp = A + A_UINTS;                   // 102.2 MB post-MLP spectrum

  // baked tables after the two planes (~1.4 MB) — nothing else writes there
  unsigned short* wf = (unsigned short*)(Bp + A_UINTS);
  float* bpk = (float*)(wf + WF_END_U16);

  k_prep<<<19, 256, 0, stream>>>(w1, b1, w2, b2, wf, bpk);
  k_fft_w<<<dim3(HH, HD / 64, 4), 256, 0, stream>>>(x, A, wf);
  k_mid<<<dim3(WC, NBLK, 4), 1024, 0, stream>>>(A, Bp, wf, bpk);
  k_ifft_w<<<dim3(HH, HD / 64, 4), 256, 0, stream>>>(A, Bp, out, wf);
}

// Round 15
// 410.915 us; speedup vs baseline: 1.1116x; 1.0220x over previous
//
#include <hip/hip_runtime.h>
#include <hip/hip_bf16.h>
#include <math.h>

// AFNO2D: rfft2(128x128, ortho) -> blockdiag complex MLP (8 x 96) -> softshrink -> irfft2 -> +bias
// B=4, H=W=128, C=768.  ALL transforms are MFMA GEMMs against baked bf16 matrices.
// Planes in ws (packed bf16 re|im per uint, [b][pos=h*65+kw][c]):
//   A = forward spectrum (k_fft_w; read-only afterwards), Bp = post-MLP spectrum (k_mid)
// Bias via spectral identity: irfft_w(rfft_w(x)) = x, so k_ifft_w transforms (A + Bp).
// k_mid v9: 512-thread WGs. Insight: the 2-WG/CU blocker was the 1024-thread shape
// (needs <=64 VGPR); two 512-thread WGs need <=128 VGPR (have ~110) and 2x77.8KB LDS
// fits in 160KB. Same 16 waves/CU as r11 but barriers sync only 8 waves and the two
// WGs overlap each other's stalls. Wave owns full ko-strip -> P2/relu handoffs are
// wave-private (r8 precedent), 9 barriers.

#define HD   768
#define NBLK 8
#define HH   128
#define WW   128
#define WC   65
#define NPOS (HH * WC)

constexpr float SC    = 0.08838834764831845f;      // 1/sqrt(128)
constexpr float TWOPI = 6.28318530717958647692f;

// table layout (ushort offsets from wf base)
constexpr int TM_OFF     = 0;        // H-DFT: 96 frags = part(3:cos,sin,-sin) x kot(8) x kk(4)
constexpr int TW_OFF     = 49152;    // W-rfft: 40 frags = mt(10) x kk(4)
constexpr int TWI_OFF    = 69632;    // W-irfft: 40 frags = mt(8) x kk(5)
constexpr int WF_OFF     = 90112;    // MLP: 16 (layer,n) x 72 frags (k_mid uses kk' 0..2 = 36)
constexpr int WF_END_U16 = 679936;   // WF_OFF + 16*72*512
constexpr size_t A_UINTS = (size_t)4 * NPOS * HD;  // 102.2 MB per plane

typedef __attribute__((ext_vector_type(8))) short short8;
typedef __attribute__((ext_vector_type(4))) float f32x4;

#define MFMA __builtin_amdgcn_mfma_f32_16x16x32_bf16

static __device__ inline unsigned short f2bf(float f) {
  __hip_bfloat16 h = __float2bfloat16(f);
  return __builtin_bit_cast(unsigned short, h);
}
static __device__ inline unsigned int pack2(float re, float im) {
  return (unsigned int)f2bf(re) | ((unsigned int)f2bf(im) << 16);
}
static __device__ inline float lo2f(unsigned int u) {
  return __builtin_bit_cast(float, u << 16);
}
static __device__ inline float hi2f(unsigned int u) {
  return __builtin_bit_cast(float, u & 0xffff0000u);
}

// ================= k_prep: bake all MFMA fragment images =================
__global__ __launch_bounds__(256) void k_prep(const float* __restrict__ w1,
                                              const float* __restrict__ b1,
                                              const float* __restrict__ w2,
                                              const float* __restrict__ b2,
                                              unsigned short* __restrict__ wf,
                                              float* __restrict__ bpk) {
  const int blk = blockIdx.x, t = threadIdx.x;
  if (blk < 16) {                      // MLP Waug B-frags (full 72) + biases
    const int layer = blk >> 3, n = blk & 7;
    const float* w  = layer ? w2 : w1;
    const float* bs = layer ? b2 : b1;
    unsigned short* dst = wf + WF_OFF + (size_t)blk * (72 * 512);
    for (int e = t; e < 72 * 512; e += 256) {
      int f = e >> 9, idx = e & 511;
      int kk = f / 12, nt = f - kk * 12;
      int lane = idx >> 3, j = idx & 7;
      int k  = kk * 32 + (lane >> 4) * 8 + j;     // 0..191
      int cc = nt * 16 + (lane & 15);             // 0..191
      float v;
      if (k < 96) v = (cc < 96) ? w[(size_t)n * 9216 + k * 96 + cc]
                                : w[(size_t)(8 + n) * 9216 + k * 96 + (cc - 96)];
      else        v = (cc < 96) ? -w[(size_t)(8 + n) * 9216 + (k - 96) * 96 + cc]
                                :  w[(size_t)n * 9216 + (k - 96) * 96 + (cc - 96)];
      dst[e] = f2bf(v);
    }
    for (int c = t; c < 192; c += 256)
      bpk[blk * 192 + c] = (c < 96) ? bs[n * 96 + c] : bs[(8 + n) * 96 + (c - 96)];
  } else if (blk == 16) {              // H-DFT twiddles: 3 parts x 32 (kot*4+kk)
    for (int e = t; e < 96 * 512; e += 256) {
      int f = e >> 9, idx = e & 511;
      int part = f >> 5, rem = f & 31, kot = rem >> 2, kk = rem & 3;
      int lane = idx >> 3, j = idx & 7;
      int ko = kot * 16 + (lane & 15);
      int r  = kk * 32 + (lane >> 4) * 8 + j;     // 0..127
      float sn, cs; sincosf((TWOPI / 128.f) * (float)((ko * r) & 127), &sn, &cs);
      float v = (part == 0) ? cs : (part == 1) ? sn : -sn;
      wf[TM_OFF + (size_t)f * 512 + idx] = f2bf(v * SC);
    }
  } else if (blk == 17) {              // W-rfft matrix: rows 0..79 = re, 80..159 = im
    for (int e = t; e < 40 * 512; e += 256) {
      int f = e >> 9, idx = e & 511;
      int mt = f >> 2, kk = f & 3;
      int lane = idx >> 3, j = idx & 7;
      int row = mt * 16 + (lane & 15);
      int r   = kk * 32 + (lane >> 4) * 8 + j;    // 0..127
      int kor = (row < 80) ? row : row - 80;
      float sn, cs; sincosf((TWOPI / 128.f) * (float)((kor * r) & 127), &sn, &cs);
      wf[TW_OFF + (size_t)f * 512 + idx] = f2bf((row < 80 ? cs : -sn) * SC);
    }
  } else {                             // W-irfft matrix: K = [re 0..79 | im 0..79]
    for (int e = t; e < 40 * 512; e += 256) {
      int f = e >> 9, idx = e & 511;
      int mt = f / 5, kk = f - mt * 5;
      int lane = idx >> 3, j = idx & 7;
      int wr = mt * 16 + (lane & 15);
      int k  = kk * 32 + (lane >> 4) * 8 + j;     // 0..159
      float v = 0.f;
      if (k < 80) {
        int kb = k;
        if (kb <= 64) {
          float sn, cs; sincosf((TWOPI / 128.f) * (float)((wr * kb) & 127), &sn, &cs);
          v = SC * ((kb == 0 || kb == 64) ? 1.f : 2.f) * cs;
        }
      } else {
        int kb = k - 80;                           // imag of bins 0,64 ignored (c2r)
        if (kb >= 1 && kb <= 63) {
          float sn, cs; sincosf((TWOPI / 128.f) * (float)((wr * kb) & 127), &sn, &cs);
          v = -2.f * SC * sn;
        }
      }
      wf[TWI_OFF + (size_t)f * 512 + idx] = f2bf(v);
    }
  }
}

// ================= k_fft_w: rfft along W via GEMM, x -> packed A =================
__global__ __launch_bounds__(256) void k_fft_w(const float* __restrict__ x,
                                               unsigned int* __restrict__ A,
                                               const unsigned short* __restrict__ wf) {
  __shared__ unsigned short Xt[64 * 136];          // [ch][r] bf16
  const int h = blockIdx.x, c0 = blockIdx.y * 64, b = blockIdx.z, t = threadIdx.x;
  const int wv = t >> 6, lane = t & 63, l15 = lane & 15, lg = lane >> 4;
  const float* xp = x + ((size_t)(b * HH + h)) * WW * HD + c0;
  for (int idx = t; idx < 128 * 64; idx += 256) {
    int r = idx >> 6, ch = idx & 63;
    Xt[ch * 136 + r] = f2bf(xp[(size_t)r * HD + ch]);
  }
  __syncthreads();
  const unsigned short* tw = wf + TW_OFF;
  f32x4 acc[10];
#pragma unroll
  for (int m = 0; m < 10; ++m) acc[m] = { 0.f, 0.f, 0.f, 0.f };
#pragma unroll
  for (int kk = 0; kk < 4; ++kk) {
    short8 bq = *(const short8*)&Xt[(wv * 16 + l15) * 136 + kk * 32 + lg * 8];
#pragma unroll
    for (int m = 0; m < 10; ++m) {
      short8 a = *(const short8*)&tw[(size_t)(m * 4 + kk) * 512 + lane * 8];
      acc[m] = MFMA(a, bq, acc[m], 0, 0, 0);
    }
  }
  unsigned int* Ao = A + ((size_t)b * NPOS + h * WC) * HD + c0 + wv * 16 + l15;
#pragma unroll
  for (int q = 0; q < 5; ++q)
#pragma unroll
    for (int r = 0; r < 4; ++r) {
      int ko = q * 16 + lg * 4 + r;
      if (ko <= 64) Ao[(size_t)ko * HD] = pack2(acc[q][r], acc[5 + q][r]);
    }
}

// ================= k_ifft_w: irfft along W of (A + Bp) via GEMM (spectral bias) ========
__global__ __launch_bounds__(256) void k_ifft_w(const unsigned int* __restrict__ A,
                                                const unsigned int* __restrict__ Bp,
                                                float* __restrict__ out,
                                                const unsigned short* __restrict__ wf) {
  __shared__ unsigned short Zt[64 * 168];          // [ch][k-stack 160]
  const int h = blockIdx.x, c0 = blockIdx.y * 64, b = blockIdx.z, t = threadIdx.x;
  const int wv = t >> 6, lane = t & 63, l15 = lane & 15, lg = lane >> 4;
  const size_t base = ((size_t)b * NPOS + h * WC) * HD + c0;
  for (int idx = t; idx < 65 * 64; idx += 256) {
    int kb = idx >> 6, ch = idx & 63;
    unsigned int uA = A[base + (size_t)kb * HD + ch];
    unsigned int uB = Bp[base + (size_t)kb * HD + ch];
    float re = lo2f(uA) + lo2f(uB);
    float im = hi2f(uA) + hi2f(uB);
    Zt[ch * 168 + kb]      = f2bf(re);
    Zt[ch * 168 + 80 + kb] = (kb == 0 || kb == 64) ? (unsigned short)0 : f2bf(im);
  }
  for (int idx = t; idx < 64 * 32; idx += 256) {   // zero-pad k 65..79 both halves
    int ch = idx >> 5, q = idx & 31;
    if (q < 30) {
      int kb = 65 + (q % 15), half = q / 15;
      Zt[ch * 168 + half * 80 + kb] = 0;
    }
  }
  __syncthreads();
  const unsigned short* twi = wf + TWI_OFF;
  f32x4 acc[8];
#pragma unroll
  for (int m = 0; m < 8; ++m) acc[m] = { 0.f, 0.f, 0.f, 0.f };
#pragma unroll
  for (int kk = 0; kk < 5; ++kk) {
    short8 bq = *(const short8*)&Zt[(wv * 16 + l15) * 168 + kk * 32 + lg * 8];
#pragma unroll
    for (int m = 0; m < 8; ++m) {
      short8 a = *(const short8*)&twi[(size_t)(m * 5 + kk) * 512 + lane * 8];
      acc[m] = MFMA(a, bq, acc[m], 0, 0, 0);
    }
  }
#pragma unroll
  for (int m = 0; m < 8; ++m)
#pragma unroll
    for (int r = 0; r < 4; ++r) {
      int wr = m * 16 + lg * 4 + r;
      size_t go = (((size_t)(b * HH + h)) * WW + wr) * HD + c0 + wv * 16 + l15;
      out[go] = acc[m][r];
    }
}

// ================= k_mid: H-DFT fwd + MLP + softshrink + H-DFT inv (512 thr) ===========
// Wave w owns ko/row strip w (16 rows), ALL 96 channels (6 co-tiles / 12 nt).
template <int FWD>
static __device__ inline void dft_gemm8(const unsigned short* Rb, const unsigned short* Ib,
                                        const unsigned short* tm, int w, int lane,
                                        f32x4* aR, f32x4* aI) {
  const int l15 = lane & 15, lg = lane >> 4;
#pragma unroll
  for (int kkr = 0; kkr < 4; ++kkr) {
    const int r0 = kkr * 32 + lg * 8;
    short8 Ac = *(const short8*)&tm[(size_t)(0 * 32 + w * 4 + kkr) * 512 + lane * 8];
    short8 As = *(const short8*)&tm[(size_t)(1 * 32 + w * 4 + kkr) * 512 + lane * 8];
    short8 An = *(const short8*)&tm[(size_t)(2 * 32 + w * 4 + kkr) * 512 + lane * 8];
#pragma unroll
    for (int c = 0; c < 6; ++c) {
      short8 zr = *(const short8*)&Rb[(c * 16 + l15) * 136 + r0];
      short8 zi = *(const short8*)&Ib[(c * 16 + l15) * 136 + r0];
      aR[c] = MFMA(Ac, zr, aR[c], 0, 0, 0);
      if constexpr (FWD) {
        aR[c] = MFMA(As, zi, aR[c], 0, 0, 0);
        aI[c] = MFMA(Ac, zi, aI[c], 0, 0, 0);
        aI[c] = MFMA(An, zr, aI[c], 0, 0, 0);
      } else {
        aR[c] = MFMA(An, zi, aR[c], 0, 0, 0);
        aI[c] = MFMA(Ac, zi, aI[c], 0, 0, 0);
        aI[c] = MFMA(As, zr, aI[c], 0, 0, 0);
      }
    }
  }
}

__global__ __launch_bounds__(512) void k_mid(const unsigned int* __restrict__ A,
                                             unsigned int* __restrict__ Bp,
                                             const unsigned short* __restrict__ wf,
                                             const float* __restrict__ bpk) {
  __shared__ unsigned short Rb[13312], Ib[13312];  // 53.2 KB plane (layout morphs)
  __shared__ unsigned short WfX[2][12 * 512];      // 24.6 KB double-buffered weight frags
  const int kv = blockIdx.x, n = blockIdx.y, b = blockIdx.z, t = threadIdx.x;
  const int w = t >> 6, lane = t & 63, l15 = lane & 15, lg = lane >> 4;
  const size_t pbase = ((size_t)b * NPOS + kv) * HD + n * 96;
  const unsigned short* tm = wf + TM_OFF;
  const unsigned short* wf1 = wf + WF_OFF + (size_t)n * (72 * 512);
  const unsigned short* wf2 = wf + WF_OFF + (size_t)(8 + n) * (72 * 512);

#define LOAD_X(BUFI, SRC, KP)                                                    \
  for (int idx = t; idx < 768; idx += 512)                                       \
    ((int4*)WfX[BUFI])[idx] = ((const int4*)((SRC) + (KP) * 12 * 512))[idx];

  // ---- P0: stage plane [ch][r] + load L1 kk'=0
  for (int idx = t; idx < 128 * 96; idx += 512) {
    int r = idx / 96, ch = idx - r * 96;
    unsigned int u = A[pbase + (size_t)r * (WC * HD) + ch];
    Rb[ch * 136 + r] = (unsigned short)(u & 0xffffu);
    Ib[ch * 136 + r] = (unsigned short)(u >> 16);
  }
  LOAD_X(0, wf1, 0);
  __syncthreads();                                  // B1

  // ---- P1: GEMM-1 fwd H-DFT (all 6 co) + load L1 kk'=1
  f32x4 aR[6], aI[6];
#pragma unroll
  for (int c = 0; c < 6; ++c) { aR[c] = {0.f,0.f,0.f,0.f}; aI[c] = {0.f,0.f,0.f,0.f}; }
  dft_gemm8<1>(Rb, Ib, tm, w, lane, aR, aI);
  LOAD_X(1, wf1, 1);
  __syncthreads();                                  // B2 (plane [ch][r] reads done)

  // ---- P2: writeback own strip as [pos][ch] (stride 104) — wave-private, no barrier
#pragma unroll
  for (int c = 0; c < 6; ++c)
#pragma unroll
    for (int r = 0; r < 4; ++r) {
      int row = w * 16 + lg * 4 + r, ch = c * 16 + l15;
      Rb[row * 104 + ch] = f2bf(aR[c][r]);
      Ib[row * 104 + ch] = f2bf(aI[c][r]);
    }

  const int row_a = (w * 16 + l15) * 104;
  f32x4 acc[12];
#pragma unroll
  for (int nt = 0; nt < 12; ++nt) {
    float bv = bpk[n * 192 + nt * 16 + l15];
    acc[nt] = { bv, bv, bv, bv };
  }

  // MLP kk-pair: MFMA kk=k0 (A=Rb row) + kk=k0+3 (A=Ib row) vs buffer's 12 frags, 12 nt
#define MLP_PAIR(BUF)                                                            \
  {                                                                              \
    short8 aRf = *(const short8*)&Rb[row_a + PK * 32 + lg * 8];                  \
    short8 aIf = *(const short8*)&Ib[row_a + PK * 32 + lg * 8];                  \
    _Pragma("unroll")                                                            \
    for (int nt = 0; nt < 12; ++nt) {                                            \
      short8 b0 = *(const short8*)&(BUF)[nt * 512 + lane * 8];                   \
      acc[nt] = MFMA(aRf, b0, acc[nt], 0, 0, 0);                                 \
      int nt2 = (nt < 6) ? nt + 6 : nt - 6;                                      \
      int4 nb = *(const int4*)&(BUF)[nt2 * 512 + lane * 8];                      \
      if (nt < 6) { nb.x ^= 0x80008000; nb.y ^= 0x80008000;                      \
                    nb.z ^= 0x80008000; nb.w ^= 0x80008000; }                    \
      acc[nt] = MFMA(aIf, __builtin_bit_cast(short8, nb), acc[nt], 0, 0, 0);     \
    }                                                                            \
  }

  // ---- MLP layer 1
  { const int PK = 0; MLP_PAIR(WfX[0]); }
  { const int PK = 1; MLP_PAIR(WfX[1]); }
  __syncthreads();                                  // B3 (X0,X1 frag reads done)
  LOAD_X(0, wf1, 2);
  LOAD_X(1, wf2, 0);
  __syncthreads();                                  // B4 (ready)
  { const int PK = 2; MLP_PAIR(WfX[0]); }

  // ---- relu -> own strip [pos][ch] (wave-private) + re-init acc for L2
#pragma unroll
  for (int i = 0; i < 6; ++i)
#pragma unroll
    for (int r = 0; r < 4; ++r) {
      int row = w * 16 + lg * 4 + r, ch = i * 16 + l15;
      Rb[row * 104 + ch] = f2bf(fmaxf(acc[i][r], 0.f));
      Ib[row * 104 + ch] = f2bf(fmaxf(acc[6 + i][r], 0.f));
    }
#pragma unroll
  for (int nt = 0; nt < 12; ++nt) {
    float bv = bpk[(8 + n) * 192 + nt * 16 + l15];
    acc[nt] = { bv, bv, bv, bv };
  }
  __syncthreads();                                  // B5 (X0 reads done)
  LOAD_X(0, wf2, 1);

  // ---- MLP layer 2
  { const int PK = 0; MLP_PAIR(WfX[1]); }
  __syncthreads();                                  // B6 (X0 ready, X1 reads done)
  LOAD_X(1, wf2, 2);
  { const int PK = 1; MLP_PAIR(WfX[0]); }
  __syncthreads();                                  // B7 (X1 ready)
  { const int PK = 2; MLP_PAIR(WfX[1]); }
  __syncthreads();                                  // B8 (all [pos][ch] reads done)

  // ---- softshrink -> [ch][ko] (stride 136)
#pragma unroll
  for (int r = 0; r < 4; ++r) {
    int ko = w * 16 + lg * 4 + r;
    float kus = (ko >= 64) ? (float)(ko - 128) : (float)ko;
    float k2v = kus * kus + (float)(kv * kv);
    float thr = fmaxf(0.01f * expf(-0.00125f * k2v), 0.0005f);
#pragma unroll
    for (int i = 0; i < 6; ++i) {
      float mr = acc[i][r], mi = acc[6 + i][r];
      float mag = sqrtf(mr * mr + mi * mi + 1e-8f);
      float sf = fmaxf(mag - thr, 0.f) / mag;
      int ch = i * 16 + l15;
      Rb[ch * 136 + ko] = f2bf(mr * sf);
      Ib[ch * 136 + ko] = f2bf(mi * sf);
    }
  }
  __syncthreads();                                  // B9

  // ---- GEMM-2: inverse H-DFT -> Bp plane
#pragma unroll
  for (int c = 0; c < 6; ++c) { aR[c] = {0.f,0.f,0.f,0.f}; aI[c] = {0.f,0.f,0.f,0.f}; }
  dft_gemm8<0>(Rb, Ib, tm, w, lane, aR, aI);
#pragma unroll
  for (int c = 0; c < 6; ++c)
#pragma unroll
    for (int r = 0; r < 4; ++r) {
      int rr = w * 16 + lg * 4 + r, ch = c * 16 + l15;
      Bp[pbase + (size_t)rr * (WC * HD) + ch] = pack2(aR[c][r], aI[c][r]);
    }
#undef MLP_PAIR
#undef LOAD_X
}

extern "C" void kernel_launch(void* const* d_in, const int* in_sizes, int n_in,
                              void* d_out, int out_size, void* d_ws, size_t ws_size,
                              hipStream_t stream) {
  const float* x  = (const float*)d_in[0];
  const float* w1 = (const float*)d_in[1];
  const float* b1 = (const float*)d_in[2];
  const float* w2 = (const float*)d_in[3];
  const float* b2 = (const float*)d_in[4];
  float* out = (float*)d_out;
  unsigned int* A  = (unsigned int*)d_ws;           // 102.2 MB forward spectrum
  unsigned int* Bp = A + A_UINTS;                   // 102.2 MB post-MLP spectrum

  // baked tables after the two planes (~1.4 MB) — nothing else writes there
  unsigned short* wf = (unsigned short*)(Bp + A_UINTS);
  float* bpk = (float*)(wf + WF_END_U16);

  k_prep<<<19, 256, 0, stream>>>(w1, b1, w2, b2, wf, bpk);
  k_fft_w<<<dim3(HH, HD / 64, 4), 256, 0, stream>>>(x, A, wf);
  k_mid<<<dim3(WC, NBLK, 4), 512, 0, stream>>>(A, Bp, wf, bpk);
  k_ifft_w<<<dim3(HH, HD / 64, 4), 256, 0, stream>>>(A, Bp, out, wf);
}